// Round 2
// baseline (724.632 us; speedup 1.0000x reference)
//
#include <hip/hip_runtime.h>

// UniversalGRU: 2-layer GRU (B=2048, T=512, D=1, H=64) + FC(64->1).
// 256 blocks x 256 threads; block owns 8 batch rows; both layers fused per t.
// MFMA 16x16x32 bf16; wave w handles n-tiles {w, w+4, w+8} so r/z/n preacts
// for h-indices [16w,16w+16) land in the same C-layout registers (gates in-reg).
// I/O dtype (fp32 vs bf16) is auto-detected from x's bit patterns.

#define T_LEN 512
#define ROWS  8

typedef float          f32x4 __attribute__((ext_vector_type(4)));
typedef __bf16         bf16x8 __attribute__((ext_vector_type(8)));
typedef unsigned short us8   __attribute__((ext_vector_type(8)));
typedef unsigned short ushort_t;

__device__ __forceinline__ float bf2f(ushort_t b){
    unsigned int u = ((unsigned int)b) << 16;
    return __uint_as_float(u);
}
__device__ __forceinline__ ushort_t f2bf(float f){
    unsigned int u = __float_as_uint(f);
    u = (u + 0x7FFFu + ((u >> 16) & 1u)) >> 16;   // RNE
    return (ushort_t)u;
}
__device__ __forceinline__ float ld_any(const void* p, int i, bool f32){
    return f32 ? ((const float*)p)[i] : bf2f(((const ushort_t*)p)[i]);
}
__device__ __forceinline__ float sigm(float x){
    return __fdividef(1.0f, 1.0f + __expf(-x));
}
__device__ __forceinline__ float tanh_f(float x){
    float xc = fminf(fmaxf(x, -15.0f), 15.0f);
    float e  = __expf(2.0f * xc);
    return 1.0f - __fdividef(2.0f, e + 1.0f);
}
__device__ __forceinline__ f32x4 mfma16(bf16x8 a, bf16x8 b, f32x4 c){
    return __builtin_amdgcn_mfma_f32_16x16x32_bf16(a, b, c, 0, 0, 0);
}
// Build a B-fragment (8 contiguous k's of W[n][k]) from either dtype.
__device__ __forceinline__ bf16x8 mk_frag(const void* W, int n, int kb, bool f32){
    us8 tmp;
    #pragma unroll
    for (int j = 0; j < 8; ++j){
        tmp[j] = f32 ? f2bf(((const float*)W)[n * 64 + kb + j])
                     : ((const ushort_t*)W)[n * 64 + kb + j];
    }
    return __builtin_bit_cast(bf16x8, tmp);
}

__global__ __launch_bounds__(256, 1) void gru_fused(
    const void* __restrict__ xv,
    const void* __restrict__ Wih0, const void* __restrict__ Whh0,
    const void* __restrict__ bih0, const void* __restrict__ bhh0,
    const void* __restrict__ Wih1, const void* __restrict__ Whh1,
    const void* __restrict__ bih1, const void* __restrict__ bhh1,
    const void* __restrict__ Wfc,  const void* __restrict__ bfc,
    void* __restrict__ outv)
{
    __shared__ float    xbuf[ROWS * T_LEN];      // staged x as f32
    __shared__ ushort_t hbufA[2][16 * 72];       // layer-0 h, A-layout bf16, dbuf
    __shared__ ushort_t hbufB[2][16 * 72];       // layer-1 h
    __shared__ float    outb[ROWS][68];          // final h2 for FC

    const int tid  = threadIdx.x;
    const int wave = tid >> 6;
    const int lane = tid & 63;
    const int c    = lane & 15;                  // MFMA col-within-tile
    const int q    = lane >> 4;                  // quad
    const int ih   = wave * 16 + c;              // h-index this lane's gates own
    const long row0 = (long)blockIdx.x * ROWS;

    // ---- dtype detection (wave-uniform): fp32 data misread as bf16 has
    // mantissa-noise exponents in even ushort slots; true bf16 never exceeds
    // exponent 150 (would mean |x| > 2^23). All threads compute the same flag.
    bool f32 = false;
    {
        const ushort_t* xs = (const ushort_t*)xv;
        for (int j = 0; j < 128; ++j){
            int e = (xs[2 * j] >> 7) & 0xFF;
            if (e > 150) f32 = true;
        }
    }

    // zero h double-buffers (h0 = 0)
    {
        ushort_t* pa = &hbufA[0][0];
        ushort_t* pb = &hbufB[0][0];
        for (int k = tid; k < 2 * 16 * 72; k += 256){ pa[k] = 0; pb[k] = 0; }
    }
    // stage x: 8 rows x 512 -> f32, coalesced 16B loads
    {
        const int r = tid >> 5;
        const int g = tid & 31;
        if (f32){
            const f32x4* src = (const f32x4*)((const float*)xv + (row0 + r) * T_LEN);
            #pragma unroll
            for (int it = 0; it < 4; ++it){
                f32x4 v = src[g + 32 * it];
                #pragma unroll
                for (int j = 0; j < 4; ++j)
                    xbuf[r * T_LEN + (g + 32 * it) * 4 + j] = v[j];
            }
        } else {
            const us8* src = (const us8*)((const ushort_t*)xv + (row0 + r) * T_LEN);
            #pragma unroll
            for (int it = 0; it < 2; ++it){
                us8 v = src[g + 32 * it];
                #pragma unroll
                for (int j = 0; j < 8; ++j)
                    xbuf[r * T_LEN + (g + 32 * it) * 8 + j] = bf2f(v[j]);
            }
        }
    }

    // Weight B-fragments in registers. B[k][n] = W[n][k]; lane: n = tile_base + c,
    // k = 32*f + 8*q + j. Gate g's tile base for wave w is 64*g + 16*w.
    bf16x8 wH0[3][2], wX1[3][2], wH1[3][2];
    #pragma unroll
    for (int g = 0; g < 3; ++g){
        const int n = g * 64 + ih;
        #pragma unroll
        for (int f = 0; f < 2; ++f){
            const int kb = f * 32 + q * 8;
            wH0[g][f] = mk_frag(Whh0, n, kb, f32);
            wX1[g][f] = mk_frag(Wih1, n, kb, f32);
            wH1[g][f] = mk_frag(Whh1, n, kb, f32);
        }
    }
    // Per-lane scalars (column ih). Biases: bih+bhh fold for r/z; bhh_n stays in h-part.
    const float w0r = ld_any(Wih0, ih, f32);
    const float w0z = ld_any(Wih0, 64 + ih, f32);
    const float w0n = ld_any(Wih0, 128 + ih, f32);
    const float b0r  = ld_any(bih0, ih, f32)       + ld_any(bhh0, ih, f32);
    const float b0z  = ld_any(bih0, 64 + ih, f32)  + ld_any(bhh0, 64 + ih, f32);
    const float b0nx = ld_any(bih0, 128 + ih, f32);
    const float b0nh = ld_any(bhh0, 128 + ih, f32);
    const float b1r  = ld_any(bih1, ih, f32)       + ld_any(bhh1, ih, f32);
    const float b1z  = ld_any(bih1, 64 + ih, f32)  + ld_any(bhh1, 64 + ih, f32);
    const float b1nx = ld_any(bih1, 128 + ih, f32);
    const float b1nh = ld_any(bhh1, 128 + ih, f32);

    f32x4 hA = {0.f, 0.f, 0.f, 0.f};   // layer-0 h, fp32-carried (rows q*4+r, col ih)
    f32x4 hB = {0.f, 0.f, 0.f, 0.f};   // layer-1 h
    const int aoff = c * 72 + q * 8;   // A-frag base: A[m=c][k=8q(+32f)]
    const int woff = q * 4;            // C-layout row base

    __syncthreads();
    int p = 0;
    for (int t = 0; t < T_LEN; ++t){
        // read prev-step h fragments (A-layout)
        us8 aA0 = *(const us8*)&hbufA[p][aoff];
        us8 aA1 = *(const us8*)&hbufA[p][aoff + 32];
        us8 aB0 = *(const us8*)&hbufB[p][aoff];
        us8 aB1 = *(const us8*)&hbufB[p][aoff + 32];

        float xm[4];
        #pragma unroll
        for (int r = 0; r < 4; ++r) xm[r] = xbuf[((woff + r) & 7) * T_LEN + t];

        f32x4 accR, accZ, accN, xn;
        #pragma unroll
        for (int r = 0; r < 4; ++r){
            accR[r] = fmaf(xm[r], w0r, b0r);
            accZ[r] = fmaf(xm[r], w0z, b0z);
            accN[r] = b0nh;
            xn[r]   = fmaf(xm[r], w0n, b0nx);
        }
        bf16x8 a0 = __builtin_bit_cast(bf16x8, aA0);
        bf16x8 a1 = __builtin_bit_cast(bf16x8, aA1);
        accR = mfma16(a0, wH0[0][0], accR); accR = mfma16(a1, wH0[0][1], accR);
        accZ = mfma16(a0, wH0[1][0], accZ); accZ = mfma16(a1, wH0[1][1], accZ);
        accN = mfma16(a0, wH0[2][0], accN); accN = mfma16(a1, wH0[2][1], accN);

        #pragma unroll
        for (int r = 0; r < 4; ++r){
            float rg = sigm(accR[r]);
            float zg = sigm(accZ[r]);
            float ng = tanh_f(xn[r] + rg * accN[r]);
            hA[r] = ng + zg * (hA[r] - ng);
            hbufA[p ^ 1][(woff + r) * 72 + ih] = f2bf(hA[r]);
        }
        __syncthreads();   // hA(t) visible

        us8 aN0 = *(const us8*)&hbufA[p ^ 1][aoff];
        us8 aN1 = *(const us8*)&hbufA[p ^ 1][aoff + 32];
        bf16x8 n0  = __builtin_bit_cast(bf16x8, aN0);
        bf16x8 n1  = __builtin_bit_cast(bf16x8, aN1);
        bf16x8 bb0 = __builtin_bit_cast(bf16x8, aB0);
        bf16x8 bb1 = __builtin_bit_cast(bf16x8, aB1);

        f32x4 aR  = {b1r, b1r, b1r, b1r};
        f32x4 aZ  = {b1z, b1z, b1z, b1z};
        f32x4 aXn = {b1nx, b1nx, b1nx, b1nx};
        f32x4 aHn = {b1nh, b1nh, b1nh, b1nh};
        aR  = mfma16(n0,  wX1[0][0], aR);  aR  = mfma16(n1,  wX1[0][1], aR);
        aR  = mfma16(bb0, wH1[0][0], aR);  aR  = mfma16(bb1, wH1[0][1], aR);
        aZ  = mfma16(n0,  wX1[1][0], aZ);  aZ  = mfma16(n1,  wX1[1][1], aZ);
        aZ  = mfma16(bb0, wH1[1][0], aZ);  aZ  = mfma16(bb1, wH1[1][1], aZ);
        aXn = mfma16(n0,  wX1[2][0], aXn); aXn = mfma16(n1,  wX1[2][1], aXn);
        aHn = mfma16(bb0, wH1[2][0], aHn); aHn = mfma16(bb1, wH1[2][1], aHn);

        #pragma unroll
        for (int r = 0; r < 4; ++r){
            float rg = sigm(aR[r]);
            float zg = sigm(aZ[r]);
            float ng = tanh_f(aXn[r] + rg * aHn[r]);
            hB[r] = ng + zg * (hB[r] - ng);
            hbufB[p ^ 1][(woff + r) * 72 + ih] = f2bf(hB[r]);
        }
        p ^= 1;
        __syncthreads();   // hB(t) visible; old buffers free for reuse
    }

    // FC epilogue: out[row] = sum_i Wfc[i]*h2[row][i] + bfc
    #pragma unroll
    for (int r = 0; r < 4; ++r){
        int m = woff + r;
        if (m < ROWS) outb[m][ih] = hB[r];
    }
    __syncthreads();
    if (tid < ROWS){
        float s = ld_any(bfc, 0, f32);
        for (int i2 = 0; i2 < 64; ++i2) s = fmaf(ld_any(Wfc, i2, f32), outb[tid][i2], s);
        if (f32) ((float*)outv)[row0 + tid] = s;
        else     ((ushort_t*)outv)[row0 + tid] = f2bf(s);
    }
}

extern "C" void kernel_launch(void* const* d_in, const int* in_sizes, int n_in,
                              void* d_out, int out_size, void* d_ws, size_t ws_size,
                              hipStream_t stream)
{
    (void)in_sizes; (void)n_in; (void)d_ws; (void)ws_size;
    const int B = out_size;            // O = 1 -> out_size == batch
    const int nblk = B / ROWS;         // 2048/8 = 256 blocks
    gru_fused<<<nblk, 256, 0, stream>>>(
        d_in[0],
        d_in[1], d_in[2], d_in[3], d_in[4],
        d_in[5], d_in[6], d_in[7], d_in[8],
        d_in[9], d_in[10],
        d_out);
}

// Round 3
// 604.445 us; speedup vs baseline: 1.1988x; 1.1988x over previous
//
#include <hip/hip_runtime.h>

// UniversalGRU: 2-layer GRU (B=2048, T=512, D=1, H=64) + FC(64->1).
// R3: layer-skewed pipeline. 256 blocks x 512 threads (8 waves).
// Waves 0-3 compute layer-0 step t; waves 4-7 compute layer-1 step t-1
// (both depend only on hA(t-1), hB(t-2)) -> ONE barrier per t.
// 2048 waves total = 2 waves/SIMD for latency hiding.
// MFMA 16x16x32 bf16; wave w owns n-tiles {w,w+4,w+8} so r/z/n preacts for
// h-cols [16w,16w+16) share C-layout registers (gates fully in-register).

#define T_LEN 512
#define ROWS  8
#define XPAD  513

typedef float          f32x4 __attribute__((ext_vector_type(4)));
typedef __bf16         bf16x8 __attribute__((ext_vector_type(8)));
typedef unsigned short us8   __attribute__((ext_vector_type(8)));
typedef unsigned short ushort_t;

__device__ __forceinline__ float bf2f(ushort_t b){
    unsigned int u = ((unsigned int)b) << 16;
    return __uint_as_float(u);
}
__device__ __forceinline__ ushort_t f2bf(float f){
    unsigned int u = __float_as_uint(f);
    u = (u + 0x7FFFu + ((u >> 16) & 1u)) >> 16;   // RNE
    return (ushort_t)u;
}
__device__ __forceinline__ float ld_any(const void* p, int i, bool f32){
    return f32 ? ((const float*)p)[i] : bf2f(((const ushort_t*)p)[i]);
}
__device__ __forceinline__ float sigm(float x){
    return __fdividef(1.0f, 1.0f + __expf(-x));
}
__device__ __forceinline__ float tanh_f(float x){
    float xc = fminf(fmaxf(x, -15.0f), 15.0f);
    float e  = __expf(2.0f * xc);
    return 1.0f - __fdividef(2.0f, e + 1.0f);
}
__device__ __forceinline__ f32x4 mfma16(bf16x8 a, bf16x8 b, f32x4 c){
    return __builtin_amdgcn_mfma_f32_16x16x32_bf16(a, b, c, 0, 0, 0);
}
// Build a B-fragment (8 contiguous k's of W[n][k]) from either dtype.
__device__ __forceinline__ bf16x8 mk_frag(const void* W, int n, int kb, bool f32){
    us8 tmp;
    #pragma unroll
    for (int j = 0; j < 8; ++j){
        tmp[j] = f32 ? f2bf(((const float*)W)[n * 64 + kb + j])
                     : ((const ushort_t*)W)[n * 64 + kb + j];
    }
    return __builtin_bit_cast(bf16x8, tmp);
}

__global__ __launch_bounds__(512, 2) void gru_fused(
    const void* __restrict__ xv,
    const void* __restrict__ Wih0, const void* __restrict__ Whh0,
    const void* __restrict__ bih0, const void* __restrict__ bhh0,
    const void* __restrict__ Wih1, const void* __restrict__ Whh1,
    const void* __restrict__ bih1, const void* __restrict__ bhh1,
    const void* __restrict__ Wfc,  const void* __restrict__ bfc,
    void* __restrict__ outv)
{
    __shared__ float    xbuf[ROWS * XPAD];       // staged x, padded stride
    __shared__ ushort_t hbufA[2][16 * 72];       // layer-0 h, A-layout bf16, dbuf
    __shared__ ushort_t hbufB[2][16 * 72];       // layer-1 h
    __shared__ float    outb[ROWS][68];          // final h2 for FC

    const int tid  = threadIdx.x;
    const int wv   = tid >> 6;                   // 0..7
    const bool isL1 = (wv >= 4);
    const int w    = wv & 3;                     // tile-group within role
    const int c    = tid & 15;                   // MFMA col-within-tile
    const int q    = (tid >> 4) & 3;             // quad
    const int ih   = w * 16 + c;                 // h-col this lane's gates own
    const long row0 = (long)blockIdx.x * ROWS;

    // dtype detection (uniform): fp32 misread as bf16 -> mantissa-noise
    // exponents in even ushort slots; true bf16 never exceeds exp 150.
    bool f32 = false;
    {
        const ushort_t* xs = (const ushort_t*)xv;
        for (int j = 0; j < 64; ++j){
            int e = (xs[2 * j] >> 7) & 0xFF;
            if (e > 150) f32 = true;
        }
    }

    // zero h double-buffers (h0 = 0; also hB(-1)=0 for the skewed start)
    {
        ushort_t* pa = &hbufA[0][0];
        ushort_t* pb = &hbufB[0][0];
        for (int k = tid; k < 2 * 16 * 72; k += 512){ pa[k] = 0; pb[k] = 0; }
    }
    // stage x: wave wv loads row wv (8 rows x 512), coalesced
    {
        const int r = wv;
        const int g = tid & 63;
        if (f32){
            const f32x4* src = (const f32x4*)((const float*)xv + (row0 + r) * T_LEN);
            #pragma unroll
            for (int it = 0; it < 2; ++it){
                f32x4 v = src[g + 64 * it];
                #pragma unroll
                for (int j = 0; j < 4; ++j)
                    xbuf[r * XPAD + (g + 64 * it) * 4 + j] = v[j];
            }
        } else {
            const us8* src = (const us8*)((const ushort_t*)xv + (row0 + r) * T_LEN);
            us8 v = src[g];
            #pragma unroll
            for (int j = 0; j < 8; ++j)
                xbuf[r * XPAD + g * 8 + j] = bf2f(v[j]);
        }
    }

    // Role-specific weights. B[k][n]=W[n][k]; lane: n = 64*g + ih, k = 32*f+8*q+j.
    bf16x8 wA[3][2], wB[3][2];                   // L0: wA=Whh0. L1: wA=Wih1, wB=Whh1.
    float sxr = 0.f, sxz = 0.f, sxn = 0.f;       // L0 scalar x-weights
    float br, bz, bnx, bnh;
    if (!isL1){
        #pragma unroll
        for (int g = 0; g < 3; ++g){
            const int n = g * 64 + ih;
            #pragma unroll
            for (int f = 0; f < 2; ++f)
                wA[g][f] = mk_frag(Whh0, n, f * 32 + q * 8, f32);
        }
        sxr = ld_any(Wih0, ih, f32);
        sxz = ld_any(Wih0, 64 + ih, f32);
        sxn = ld_any(Wih0, 128 + ih, f32);
        br  = ld_any(bih0, ih, f32)       + ld_any(bhh0, ih, f32);
        bz  = ld_any(bih0, 64 + ih, f32)  + ld_any(bhh0, 64 + ih, f32);
        bnx = ld_any(bih0, 128 + ih, f32);
        bnh = ld_any(bhh0, 128 + ih, f32);
    } else {
        #pragma unroll
        for (int g = 0; g < 3; ++g){
            const int n = g * 64 + ih;
            #pragma unroll
            for (int f = 0; f < 2; ++f){
                wA[g][f] = mk_frag(Wih1, n, f * 32 + q * 8, f32);
                wB[g][f] = mk_frag(Whh1, n, f * 32 + q * 8, f32);
            }
        }
        br  = ld_any(bih1, ih, f32)       + ld_any(bhh1, ih, f32);
        bz  = ld_any(bih1, 64 + ih, f32)  + ld_any(bhh1, 64 + ih, f32);
        bnx = ld_any(bih1, 128 + ih, f32);
        bnh = ld_any(bhh1, 128 + ih, f32);
    }

    f32x4 hreg = {0.f, 0.f, 0.f, 0.f};           // L0: hA rows; L1: hB rows (fp32)
    const int aoff = c * 72 + q * 8;             // A-frag base: A[m=c][k=8q(+32f)]
    const int woff = q * 4;                      // C-layout row base

    __syncthreads();

    for (int t = 0; t < T_LEN; ++t){
        const int p = t & 1;
        if (!isL1){
            // ---- layer 0, step t: hA(t) = GRU0(x(t), hA(t-1))
            us8 a0u = *(const us8*)&hbufA[p][aoff];
            us8 a1u = *(const us8*)&hbufA[p][aoff + 32];
            float xm[4];
            #pragma unroll
            for (int r = 0; r < 4; ++r) xm[r] = xbuf[((woff + r) & 7) * XPAD + t];
            f32x4 aR, aZ, aN, xn;
            #pragma unroll
            for (int r = 0; r < 4; ++r){
                aR[r] = fmaf(xm[r], sxr, br);
                aZ[r] = fmaf(xm[r], sxz, bz);
                aN[r] = bnh;
                xn[r] = fmaf(xm[r], sxn, bnx);
            }
            bf16x8 a0 = __builtin_bit_cast(bf16x8, a0u);
            bf16x8 a1 = __builtin_bit_cast(bf16x8, a1u);
            aR = mfma16(a0, wA[0][0], aR); aR = mfma16(a1, wA[0][1], aR);
            aZ = mfma16(a0, wA[1][0], aZ); aZ = mfma16(a1, wA[1][1], aZ);
            aN = mfma16(a0, wA[2][0], aN); aN = mfma16(a1, wA[2][1], aN);
            #pragma unroll
            for (int r = 0; r < 4; ++r){
                float rg = sigm(aR[r]);
                float zg = sigm(aZ[r]);
                float ng = tanh_f(xn[r] + rg * aN[r]);
                hreg[r] = ng + zg * (hreg[r] - ng);
                hbufA[p ^ 1][(woff + r) * 72 + ih] = f2bf(hreg[r]);
            }
        } else if (t > 0){
            // ---- layer 1, step t-1: hB(t-1) = GRU1(hA(t-1), hB(t-2))
            us8 a0u = *(const us8*)&hbufA[p][aoff];        // hA(t-1)
            us8 a1u = *(const us8*)&hbufA[p][aoff + 32];
            us8 b0u = *(const us8*)&hbufB[p][aoff];        // hB(t-2)
            us8 b1u = *(const us8*)&hbufB[p][aoff + 32];
            bf16x8 a0 = __builtin_bit_cast(bf16x8, a0u);
            bf16x8 a1 = __builtin_bit_cast(bf16x8, a1u);
            bf16x8 b0 = __builtin_bit_cast(bf16x8, b0u);
            bf16x8 b1 = __builtin_bit_cast(bf16x8, b1u);
            f32x4 aR  = {br, br, br, br};
            f32x4 aZ  = {bz, bz, bz, bz};
            f32x4 aXn = {bnx, bnx, bnx, bnx};
            f32x4 aHn = {bnh, bnh, bnh, bnh};
            aR  = mfma16(a0, wA[0][0], aR);  aR  = mfma16(a1, wA[0][1], aR);
            aR  = mfma16(b0, wB[0][0], aR);  aR  = mfma16(b1, wB[0][1], aR);
            aZ  = mfma16(a0, wA[1][0], aZ);  aZ  = mfma16(a1, wA[1][1], aZ);
            aZ  = mfma16(b0, wB[1][0], aZ);  aZ  = mfma16(b1, wB[1][1], aZ);
            aXn = mfma16(a0, wA[2][0], aXn); aXn = mfma16(a1, wA[2][1], aXn);
            aHn = mfma16(b0, wB[2][0], aHn); aHn = mfma16(b1, wB[2][1], aHn);
            #pragma unroll
            for (int r = 0; r < 4; ++r){
                float rg = sigm(aR[r]);
                float zg = sigm(aZ[r]);
                float ng = tanh_f(aXn[r] + rg * aHn[r]);
                hreg[r] = ng + zg * (hreg[r] - ng);
                hbufB[p ^ 1][(woff + r) * 72 + ih] = f2bf(hreg[r]);
            }
        }
        __syncthreads();
    }

    // Epilogue: L1 waves compute the final step hB(511) from hA(511), hB(510)
    // (both sit in buffer 0 after 512 iterations).
    if (isL1){
        us8 a0u = *(const us8*)&hbufA[0][aoff];
        us8 a1u = *(const us8*)&hbufA[0][aoff + 32];
        us8 b0u = *(const us8*)&hbufB[0][aoff];
        us8 b1u = *(const us8*)&hbufB[0][aoff + 32];
        bf16x8 a0 = __builtin_bit_cast(bf16x8, a0u);
        bf16x8 a1 = __builtin_bit_cast(bf16x8, a1u);
        bf16x8 b0 = __builtin_bit_cast(bf16x8, b0u);
        bf16x8 b1 = __builtin_bit_cast(bf16x8, b1u);
        f32x4 aR  = {br, br, br, br};
        f32x4 aZ  = {bz, bz, bz, bz};
        f32x4 aXn = {bnx, bnx, bnx, bnx};
        f32x4 aHn = {bnh, bnh, bnh, bnh};
        aR  = mfma16(a0, wA[0][0], aR);  aR  = mfma16(a1, wA[0][1], aR);
        aR  = mfma16(b0, wB[0][0], aR);  aR  = mfma16(b1, wB[0][1], aR);
        aZ  = mfma16(a0, wA[1][0], aZ);  aZ  = mfma16(a1, wA[1][1], aZ);
        aZ  = mfma16(b0, wB[1][0], aZ);  aZ  = mfma16(b1, wB[1][1], aZ);
        aXn = mfma16(a0, wA[2][0], aXn); aXn = mfma16(a1, wA[2][1], aXn);
        aHn = mfma16(b0, wB[2][0], aHn); aHn = mfma16(b1, wB[2][1], aHn);
        #pragma unroll
        for (int r = 0; r < 4; ++r){
            float rg = sigm(aR[r]);
            float zg = sigm(aZ[r]);
            float ng = tanh_f(aXn[r] + rg * aHn[r]);
            float hf = ng + zg * (hreg[r] - ng);
            int m = woff + r;
            if (m < ROWS) outb[m][ih] = hf;
        }
    }
    __syncthreads();

    // FC: out[row] = sum_i Wfc[i]*h2[row][i] + bfc
    if (tid < ROWS){
        float s = ld_any(bfc, 0, f32);
        for (int i2 = 0; i2 < 64; ++i2) s = fmaf(ld_any(Wfc, i2, f32), outb[tid][i2], s);
        if (f32) ((float*)outv)[row0 + tid] = s;
        else     ((ushort_t*)outv)[row0 + tid] = f2bf(s);
    }
}

extern "C" void kernel_launch(void* const* d_in, const int* in_sizes, int n_in,
                              void* d_out, int out_size, void* d_ws, size_t ws_size,
                              hipStream_t stream)
{
    (void)in_sizes; (void)n_in; (void)d_ws; (void)ws_size;
    const int B = out_size;            // O = 1 -> out_size == batch
    const int nblk = B / ROWS;         // 2048/8 = 256 blocks
    gru_fused<<<nblk, 512, 0, stream>>>(
        d_in[0],
        d_in[1], d_in[2], d_in[3], d_in[4],
        d_in[5], d_in[6], d_in[7], d_in[8],
        d_in[9], d_in[10],
        d_out);
}

// Round 4
// 470.833 us; speedup vs baseline: 1.5390x; 1.2838x over previous
//
#include <hip/hip_runtime.h>

// UniversalGRU: 2-layer GRU (B=2048, T=512, D=1, H=64) + FC(64->1).
// R4: layer-skewed pipeline (1 barrier/t) + gate-lane redistribution.
// 256 blocks x 512 threads; waves 0-3 = layer-0 step t, waves 4-7 = layer-1
// step t-1. MFMA M=16 tile has only 8 real rows; after MFMA, regs 2-3 of
// lanes 0-31 are shuffled to lanes 32-63 so all 64 lanes process exactly
// 2 REAL gate triples (was 4 half-fake) -> halves transcendental issue.

#define T_LEN 512
#define ROWS  8
#define XPAD  513

typedef float          f32x4 __attribute__((ext_vector_type(4)));
typedef __bf16         bf16x8 __attribute__((ext_vector_type(8)));
typedef unsigned short us8   __attribute__((ext_vector_type(8)));
typedef unsigned short ushort_t;

__device__ __forceinline__ float bf2f(ushort_t b){
    unsigned int u = ((unsigned int)b) << 16;
    return __uint_as_float(u);
}
__device__ __forceinline__ ushort_t f2bf(float f){
    unsigned int u = __float_as_uint(f);
    u = (u + 0x7FFFu + ((u >> 16) & 1u)) >> 16;   // RNE
    return (ushort_t)u;
}
__device__ __forceinline__ float ld_any(const void* p, int i, bool f32){
    return f32 ? ((const float*)p)[i] : bf2f(((const ushort_t*)p)[i]);
}
// sigm/tanh via exp2+rcp; saturate correctly at +-inf without clamps.
__device__ __forceinline__ float sigm(float x){
    float e = __expf(-x);                 // v_mul + v_exp
    return __fdividef(1.0f, 1.0f + e);    // v_rcp
}
__device__ __forceinline__ float tanh_f(float x){
    float e = __expf(2.0f * x);
    return fmaf(-2.0f, __fdividef(1.0f, e + 1.0f), 1.0f);
}
__device__ __forceinline__ f32x4 mfma16(bf16x8 a, bf16x8 b, f32x4 c){
    return __builtin_amdgcn_mfma_f32_16x16x32_bf16(a, b, c, 0, 0, 0);
}
// Build a B-fragment (8 contiguous k's of W[n][k]) from either dtype.
__device__ __forceinline__ bf16x8 mk_frag(const void* W, int n, int kb, bool f32){
    us8 tmp;
    #pragma unroll
    for (int j = 0; j < 8; ++j){
        tmp[j] = f32 ? f2bf(((const float*)W)[n * 64 + kb + j])
                     : ((const ushort_t*)W)[n * 64 + kb + j];
    }
    return __builtin_bit_cast(bf16x8, tmp);
}

__global__ __launch_bounds__(512, 2) void gru_fused(
    const void* __restrict__ xv,
    const void* __restrict__ Wih0, const void* __restrict__ Whh0,
    const void* __restrict__ bih0, const void* __restrict__ bhh0,
    const void* __restrict__ Wih1, const void* __restrict__ Whh1,
    const void* __restrict__ bih1, const void* __restrict__ bhh1,
    const void* __restrict__ Wfc,  const void* __restrict__ bfc,
    void* __restrict__ outv)
{
    __shared__ float    xbuf[ROWS * XPAD];       // staged x, padded stride
    __shared__ ushort_t hbufA[2][16 * 72];       // layer-0 h, A-layout bf16, dbuf
    __shared__ ushort_t hbufB[2][16 * 72];       // layer-1 h
    __shared__ float    outb[ROWS][68];          // final h2 for FC

    const int tid  = threadIdx.x;
    const int wv   = tid >> 6;                   // 0..7
    const bool isL1 = (wv >= 4);
    const int w    = wv & 3;                     // tile-group within role
    const int c    = tid & 15;                   // MFMA col-within-tile
    const int q    = (tid >> 4) & 3;             // quad
    const int ih   = w * 16 + c;                 // h-col this lane's gates own
    const int hi   = q >> 1;                     // upper-half-wave flag
    const int mrow = (q & 1) * 4 + hi * 2;       // first of this lane's 2 REAL rows
    const long row0 = (long)blockIdx.x * ROWS;

    // dtype detection (uniform): fp32 misread as bf16 -> mantissa-noise
    // exponents in even ushort slots; true bf16 never exceeds exp 150.
    bool f32 = false;
    {
        const ushort_t* xs = (const ushort_t*)xv;
        for (int j = 0; j < 64; ++j){
            int e = (xs[2 * j] >> 7) & 0xFF;
            if (e > 150) f32 = true;
        }
    }

    // zero h double-buffers (h0 = 0; also hB(-1)=0 for the skewed start)
    {
        ushort_t* pa = &hbufA[0][0];
        ushort_t* pb = &hbufB[0][0];
        for (int k = tid; k < 2 * 16 * 72; k += 512){ pa[k] = 0; pb[k] = 0; }
    }
    // stage x: wave wv loads row wv (8 rows x 512), coalesced
    {
        const int r = wv;
        const int g = tid & 63;
        if (f32){
            const f32x4* src = (const f32x4*)((const float*)xv + (row0 + r) * T_LEN);
            #pragma unroll
            for (int it = 0; it < 2; ++it){
                f32x4 v = src[g + 64 * it];
                #pragma unroll
                for (int j = 0; j < 4; ++j)
                    xbuf[r * XPAD + (g + 64 * it) * 4 + j] = v[j];
            }
        } else {
            const us8* src = (const us8*)((const ushort_t*)xv + (row0 + r) * T_LEN);
            us8 v = src[g];
            #pragma unroll
            for (int j = 0; j < 8; ++j)
                xbuf[r * XPAD + g * 8 + j] = bf2f(v[j]);
        }
    }

    // Role-specific weights. B[k][n]=W[n][k]; lane: n = 64*g + ih, k = 32*f+8*q+j.
    bf16x8 wA[3][2], wB[3][2];                   // L0: wA=Whh0. L1: wA=Wih1, wB=Whh1.
    float sxr = 0.f, sxz = 0.f, sxn = 0.f;       // L0 scalar x-weights
    float br, bz, bnx, bnh;
    if (!isL1){
        #pragma unroll
        for (int g = 0; g < 3; ++g){
            const int n = g * 64 + ih;
            #pragma unroll
            for (int f = 0; f < 2; ++f)
                wA[g][f] = mk_frag(Whh0, n, f * 32 + q * 8, f32);
        }
        sxr = ld_any(Wih0, ih, f32);
        sxz = ld_any(Wih0, 64 + ih, f32);
        sxn = ld_any(Wih0, 128 + ih, f32);
        br  = ld_any(bih0, ih, f32)       + ld_any(bhh0, ih, f32);
        bz  = ld_any(bih0, 64 + ih, f32)  + ld_any(bhh0, 64 + ih, f32);
        bnx = ld_any(bih0, 128 + ih, f32);
        bnh = ld_any(bhh0, 128 + ih, f32);
    } else {
        #pragma unroll
        for (int g = 0; g < 3; ++g){
            const int n = g * 64 + ih;
            #pragma unroll
            for (int f = 0; f < 2; ++f){
                wA[g][f] = mk_frag(Wih1, n, f * 32 + q * 8, f32);
                wB[g][f] = mk_frag(Whh1, n, f * 32 + q * 8, f32);
            }
        }
        br  = ld_any(bih1, ih, f32)       + ld_any(bhh1, ih, f32);
        bz  = ld_any(bih1, 64 + ih, f32)  + ld_any(bhh1, 64 + ih, f32);
        bnx = ld_any(bih1, 128 + ih, f32);
        bnh = ld_any(bhh1, 128 + ih, f32);
    }

    float h2[2] = {0.f, 0.f};          // fp32-carried h for this lane's 2 real rows
    const int aoff = c * 72 + q * 8;   // A-frag base: A[m=c][k=8q(+32f)]
    const int woff = q * 4;            // C-layout row base (MFMA view)

    __syncthreads();

    #pragma unroll 2
    for (int t = 0; t < T_LEN; ++t){
        const int p = t & 1;
        if (!isL1){
            // ---- layer 0, step t: hA(t) = GRU0(x(t), hA(t-1))
            us8 a0u = *(const us8*)&hbufA[p][aoff];
            us8 a1u = *(const us8*)&hbufA[p][aoff + 32];
            float xm[4];
            #pragma unroll
            for (int r = 0; r < 4; ++r) xm[r] = xbuf[((woff + r) & 7) * XPAD + t];
            f32x4 aR, aZ, aN, xn;
            #pragma unroll
            for (int r = 0; r < 4; ++r){
                aR[r] = fmaf(xm[r], sxr, br);
                aZ[r] = fmaf(xm[r], sxz, bz);
                aN[r] = bnh;
                xn[r] = fmaf(xm[r], sxn, bnx);
            }
            bf16x8 a0 = __builtin_bit_cast(bf16x8, a0u);
            bf16x8 a1 = __builtin_bit_cast(bf16x8, a1u);
            aR = mfma16(a0, wA[0][0], aR); aR = mfma16(a1, wA[0][1], aR);
            aZ = mfma16(a0, wA[1][0], aZ); aZ = mfma16(a1, wA[1][1], aZ);
            aN = mfma16(a0, wA[2][0], aN); aN = mfma16(a1, wA[2][1], aN);
            // redistribute: regs 2-3 of lanes 0-31 -> lanes 32-63
            float sR0 = __shfl_up(aR[2], 32), sR1 = __shfl_up(aR[3], 32);
            float sZ0 = __shfl_up(aZ[2], 32), sZ1 = __shfl_up(aZ[3], 32);
            float sN0 = __shfl_up(aN[2], 32), sN1 = __shfl_up(aN[3], 32);
            float sX0 = __shfl_up(xn[2], 32), sX1 = __shfl_up(xn[3], 32);
            float gR[2] = { hi ? sR0 : aR[0], hi ? sR1 : aR[1] };
            float gZ[2] = { hi ? sZ0 : aZ[0], hi ? sZ1 : aZ[1] };
            float gN[2] = { hi ? sN0 : aN[0], hi ? sN1 : aN[1] };
            float gX[2] = { hi ? sX0 : xn[0], hi ? sX1 : xn[1] };
            #pragma unroll
            for (int j = 0; j < 2; ++j){
                float rg = sigm(gR[j]);
                float zg = sigm(gZ[j]);
                float ng = tanh_f(gX[j] + rg * gN[j]);
                h2[j] = ng + zg * (h2[j] - ng);
                hbufA[p ^ 1][(mrow + j) * 72 + ih] = f2bf(h2[j]);
            }
        } else if (t > 0){
            // ---- layer 1, step t-1: hB(t-1) = GRU1(hA(t-1), hB(t-2))
            us8 a0u = *(const us8*)&hbufA[p][aoff];        // hA(t-1)
            us8 a1u = *(const us8*)&hbufA[p][aoff + 32];
            us8 b0u = *(const us8*)&hbufB[p][aoff];        // hB(t-2)
            us8 b1u = *(const us8*)&hbufB[p][aoff + 32];
            bf16x8 a0 = __builtin_bit_cast(bf16x8, a0u);
            bf16x8 a1 = __builtin_bit_cast(bf16x8, a1u);
            bf16x8 b0 = __builtin_bit_cast(bf16x8, b0u);
            bf16x8 b1 = __builtin_bit_cast(bf16x8, b1u);
            f32x4 aR  = {br, br, br, br};
            f32x4 aZ  = {bz, bz, bz, bz};
            f32x4 aXn = {bnx, bnx, bnx, bnx};
            f32x4 aHn = {bnh, bnh, bnh, bnh};
            aR  = mfma16(a0, wA[0][0], aR);  aR  = mfma16(a1, wA[0][1], aR);
            aR  = mfma16(b0, wB[0][0], aR);  aR  = mfma16(b1, wB[0][1], aR);
            aZ  = mfma16(a0, wA[1][0], aZ);  aZ  = mfma16(a1, wA[1][1], aZ);
            aZ  = mfma16(b0, wB[1][0], aZ);  aZ  = mfma16(b1, wB[1][1], aZ);
            aXn = mfma16(a0, wA[2][0], aXn); aXn = mfma16(a1, wA[2][1], aXn);
            aHn = mfma16(b0, wB[2][0], aHn); aHn = mfma16(b1, wB[2][1], aHn);
            float sR0 = __shfl_up(aR[2], 32),  sR1 = __shfl_up(aR[3], 32);
            float sZ0 = __shfl_up(aZ[2], 32),  sZ1 = __shfl_up(aZ[3], 32);
            float sX0 = __shfl_up(aXn[2], 32), sX1 = __shfl_up(aXn[3], 32);
            float sN0 = __shfl_up(aHn[2], 32), sN1 = __shfl_up(aHn[3], 32);
            float gR[2] = { hi ? sR0 : aR[0],  hi ? sR1 : aR[1] };
            float gZ[2] = { hi ? sZ0 : aZ[0],  hi ? sZ1 : aZ[1] };
            float gX[2] = { hi ? sX0 : aXn[0], hi ? sX1 : aXn[1] };
            float gN[2] = { hi ? sN0 : aHn[0], hi ? sN1 : aHn[1] };
            #pragma unroll
            for (int j = 0; j < 2; ++j){
                float rg = sigm(gR[j]);
                float zg = sigm(gZ[j]);
                float ng = tanh_f(gX[j] + rg * gN[j]);
                h2[j] = ng + zg * (h2[j] - ng);
                hbufB[p ^ 1][(mrow + j) * 72 + ih] = f2bf(h2[j]);
            }
        }
        __syncthreads();
    }

    // Epilogue: L1 waves compute the final step hB(511) from hA(511), hB(510)
    // (both sit in buffer 0 after 512 iterations).
    if (isL1){
        us8 a0u = *(const us8*)&hbufA[0][aoff];
        us8 a1u = *(const us8*)&hbufA[0][aoff + 32];
        us8 b0u = *(const us8*)&hbufB[0][aoff];
        us8 b1u = *(const us8*)&hbufB[0][aoff + 32];
        bf16x8 a0 = __builtin_bit_cast(bf16x8, a0u);
        bf16x8 a1 = __builtin_bit_cast(bf16x8, a1u);
        bf16x8 b0 = __builtin_bit_cast(bf16x8, b0u);
        bf16x8 b1 = __builtin_bit_cast(bf16x8, b1u);
        f32x4 aR  = {br, br, br, br};
        f32x4 aZ  = {bz, bz, bz, bz};
        f32x4 aXn = {bnx, bnx, bnx, bnx};
        f32x4 aHn = {bnh, bnh, bnh, bnh};
        aR  = mfma16(a0, wA[0][0], aR);  aR  = mfma16(a1, wA[0][1], aR);
        aR  = mfma16(b0, wB[0][0], aR);  aR  = mfma16(b1, wB[0][1], aR);
        aZ  = mfma16(a0, wA[1][0], aZ);  aZ  = mfma16(a1, wA[1][1], aZ);
        aZ  = mfma16(b0, wB[1][0], aZ);  aZ  = mfma16(b1, wB[1][1], aZ);
        aXn = mfma16(a0, wA[2][0], aXn); aXn = mfma16(a1, wA[2][1], aXn);
        aHn = mfma16(b0, wB[2][0], aHn); aHn = mfma16(b1, wB[2][1], aHn);
        float sR0 = __shfl_up(aR[2], 32),  sR1 = __shfl_up(aR[3], 32);
        float sZ0 = __shfl_up(aZ[2], 32),  sZ1 = __shfl_up(aZ[3], 32);
        float sX0 = __shfl_up(aXn[2], 32), sX1 = __shfl_up(aXn[3], 32);
        float sN0 = __shfl_up(aHn[2], 32), sN1 = __shfl_up(aHn[3], 32);
        float gR[2] = { hi ? sR0 : aR[0],  hi ? sR1 : aR[1] };
        float gZ[2] = { hi ? sZ0 : aZ[0],  hi ? sZ1 : aZ[1] };
        float gX[2] = { hi ? sX0 : aXn[0], hi ? sX1 : aXn[1] };
        float gN[2] = { hi ? sN0 : aHn[0], hi ? sN1 : aHn[1] };
        #pragma unroll
        for (int j = 0; j < 2; ++j){
            float rg = sigm(gR[j]);
            float zg = sigm(gZ[j]);
            float ng = tanh_f(gX[j] + rg * gN[j]);
            float hf = ng + zg * (h2[j] - ng);
            outb[mrow + j][ih] = hf;
        }
    }
    __syncthreads();

    // FC: out[row] = sum_i Wfc[i]*h2[row][i] + bfc
    if (tid < ROWS){
        float s = ld_any(bfc, 0, f32);
        for (int i2 = 0; i2 < 64; ++i2) s = fmaf(ld_any(Wfc, i2, f32), outb[tid][i2], s);
        if (f32) ((float*)outv)[row0 + tid] = s;
        else     ((ushort_t*)outv)[row0 + tid] = f2bf(s);
    }
}

extern "C" void kernel_launch(void* const* d_in, const int* in_sizes, int n_in,
                              void* d_out, int out_size, void* d_ws, size_t ws_size,
                              hipStream_t stream)
{
    (void)in_sizes; (void)n_in; (void)d_ws; (void)ws_size;
    const int B = out_size;            // O = 1 -> out_size == batch
    const int nblk = B / ROWS;         // 2048/8 = 256 blocks
    gru_fused<<<nblk, 512, 0, stream>>>(
        d_in[0],
        d_in[1], d_in[2], d_in[3], d_in[4],
        d_in[5], d_in[6], d_in[7], d_in[8],
        d_in[9], d_in[10],
        d_out);
}